// Round 3
// baseline (589.225 us; speedup 1.0000x reference)
//
#include <hip/hip_runtime.h>

static constexpr int T_LEN    = 4096;   // time axis length
static constexpr int SEG      = 2048;   // per-wave segment (2 waves per row)
static constexpr int PER_LANE = 32;     // contiguous elems per lane
#define EPSV 1e-6f

typedef float vfloat4 __attribute__((ext_vector_type(4)));

__device__ __forceinline__ float fexp2(float x) { return __builtin_amdgcn_exp2f(x); }
__device__ __forceinline__ float flog2(float x) { return __builtin_amdgcn_logf(x); }

// order-preserving float<->uint transform (works for negatives too)
__device__ __forceinline__ unsigned int flip_f(float f) {
    unsigned int u = __float_as_uint(f);
    return u ^ ((u >> 31) ? 0xFFFFFFFFu : 0x80000000u);
}
__device__ __forceinline__ float unflip_f(unsigned int u) {
    u ^= ((u >> 31) ? 0x80000000u : 0xFFFFFFFFu);
    return __uint_as_float(u);
}

__global__ void init_ws(unsigned int* ws) {
    ws[0] = 0xFFFFFFFFu;  // min slot (transformed +max)
    ws[1] = 0x00000000u;  // max slot (transformed -max)
}

// Layout: 2 waves per row (wave w owns [w*2048, (w+1)*2048)); lane owns 32
// contiguous elems held in EIGHT NAMED float4 variables (v0..v7).
// NOTE: rounds 1-2 used float4 v[N] arrays -> never promoted out of scratch
// (VGPR_Count 32-40 + ~380MB scratch WRITE_SIZE). Named scalars are SSA
// values from birth and cannot be demoted. Do not reintroduce an array here.
// Phase 1: 8 dwordx4 preload + 4-way-ILP Horner (ratio a^4) -> lane sum W.
// Phase 2: one 6-step intra-wave shfl scan (lane ratio a^32) + LDS cross-wave
//          carry (wave-0 segment total decayed by a^2048) + seed E[0] trick.
// Phase 3: serial m-chain (32 FMAs) + independent pcen transcendentals.
// PASS 0 tracks min/max of u = E*(eps+M)^-alpha + delta (monotone pre-pow),
// converted to p-domain once per block. delta^r dropped (shift-invariant).
template <int PASS>
__launch_bounds__(256, 4)
__global__ void pcen_pass(const float* __restrict__ E,
                          const float* __restrict__ sp,
                          const float* __restrict__ ap,
                          const float* __restrict__ dp,
                          const float* __restrict__ rp,
                          float* __restrict__ out,
                          unsigned int* __restrict__ ws,
                          int rows)
{
    const int tid  = threadIdx.x;
    const int lane = tid & 63;
    const int wvg  = tid >> 6;   // 0..3
    const int w    = wvg & 1;    // wave-in-row
    const int rib  = wvg >> 1;   // row-in-block 0..1
    const int row  = blockIdx.x * 2 + rib;

    float s = sp[0];
    s = fminf(fmaxf(s, 0.0f), 1.0f);
    const float a     = 1.0f - s;
    const float na    = -ap[0];
    const float delta = dp[0];
    const float r     = rp[0];

    // powers of a by repeated squaring
    const float a2 = a * a, a4 = a2 * a2, a8 = a4 * a4,
                a16 = a8 * a8, a32 = a16 * a16;
    const float a64 = a32 * a32, a128 = a64 * a64, a256 = a128 * a128,
                a512 = a256 * a256, a1024 = a512 * a512, a2048 = a1024 * a1024;

    // pwl = a^(32*lane): decay across earlier lanes of this wave's segment
    float pwl;
    if (a > 0.0f) pwl = fexp2((float)(PER_LANE * lane) * flog2(a));
    else          pwl = (lane == 0) ? 1.0f : 0.0f;

    float scale = 0.0f, bias = 0.0f;
    if (PASS == 1) {
        const float pmin = unflip_f(ws[0]);
        const float pmax = unflip_f(ws[1]);
        const float inv  = 2.0f / (pmax - pmin);
        scale = inv;
        bias  = __builtin_fmaf(-pmin, inv, -1.0f);
    }

    __shared__ float lds_tot[2];  // wave-0 inclusive segment total, per row
    __shared__ float lds_e0[2];   // row seed E[0], per row

    float vmin = __builtin_inff(), vmax = -__builtin_inff();

    // named registers for the lane's 32 elements -- NOT an array (see note)
    float4 v0, v1, v2, v3, v4, v5, v6, v7;
    float  Sex = 0.0f;

    const bool active = (row < rows);

    if (active) {
        const float4* __restrict__ src =
            (const float4*)(E + (size_t)row * T_LEN + w * SEG) + lane * 8;

        // ---- Phase 1: preload lane's 32 elems (8 dwordx4, full MLP) ----
        v0 = src[0]; v1 = src[1]; v2 = src[2]; v3 = src[3];
        v4 = src[4]; v5 = src[5]; v6 = src[6]; v7 = src[7];

        // Lane-local weighted sum via 4 interleaved Horner chains (ratio a^4)
        float w0 = 0.0f, w1 = 0.0f, w2 = 0.0f, w3 = 0.0f;
#define HORNER(V)                               \
        w0 = __builtin_fmaf(a4, w0, (V).x);     \
        w1 = __builtin_fmaf(a4, w1, (V).y);     \
        w2 = __builtin_fmaf(a4, w2, (V).z);     \
        w3 = __builtin_fmaf(a4, w3, (V).w);
        HORNER(v0) HORNER(v1) HORNER(v2) HORNER(v3)
        HORNER(v4) HORNER(v5) HORNER(v6) HORNER(v7)
#undef HORNER
        // W = s * (a^3 w0 + a^2 w1 + a w2 + w3)
        float W = s * __builtin_fmaf(a, __builtin_fmaf(a, __builtin_fmaf(a, w0, w1), w2), w3);

        // ---- Phase 2: inclusive intra-wave scan, lane ratio a^32 ----
        float S = W, t;
        t = __shfl_up(S, 1, 64);  if (lane >= 1)  S = __builtin_fmaf(a32,   t, S);
        t = __shfl_up(S, 2, 64);  if (lane >= 2)  S = __builtin_fmaf(a64,   t, S);
        t = __shfl_up(S, 4, 64);  if (lane >= 4)  S = __builtin_fmaf(a128,  t, S);
        t = __shfl_up(S, 8, 64);  if (lane >= 8)  S = __builtin_fmaf(a256,  t, S);
        t = __shfl_up(S, 16, 64); if (lane >= 16) S = __builtin_fmaf(a512,  t, S);
        t = __shfl_up(S, 32, 64); if (lane >= 32) S = __builtin_fmaf(a1024, t, S);

        Sex = __shfl_up(S, 1, 64);   // exclusive within-wave prefix
        if (lane == 0) Sex = 0.0f;

        if (w == 0) {
            if (lane == 63) lds_tot[rib] = S;      // segment total
            if (lane == 0)  lds_e0[rib]  = v0.x;   // row seed E[0]
        }
    }

    __syncthreads();  // unconditional: all waves reach this

    if (active) {
        const float tot0 = lds_tot[rib];
        const float e0   = lds_e0[rib];

        // m just before this lane's chunk:
        //   m = E0 * a^(2048w + 32L) + (w==1 ? tot0 * a^(32L) : 0) + Sex
        const float base = (w == 1) ? __builtin_fmaf(a2048, e0, tot0) : e0;
        float m = __builtin_fmaf(pwl, base, Sex);

        float* __restrict__ drow =
            out + (size_t)row * T_LEN + w * SEG + lane * PER_LANE;

        // ---- Phase 3: serial m-chain + independent pcen work ----
#define PCEN1(X, OREF)                                                        \
        { const float x = (X);                                                \
          m = __builtin_fmaf(a, m, s * x);                                    \
          const float u = __builtin_fmaf(x, fexp2(na * flog2(EPSV + m)), delta); \
          if (PASS == 0) { vmin = fminf(vmin, u); vmax = fmaxf(vmax, u); }    \
          else OREF = __builtin_fmaf(fexp2(r * flog2(u)), scale, bias); }

#define PCEN4(V, J)                                                           \
        { float4 o;                                                           \
          PCEN1((V).x, o.x) PCEN1((V).y, o.y)                                 \
          PCEN1((V).z, o.z) PCEN1((V).w, o.w)                                 \
          if (PASS == 1) {                                                    \
              vfloat4 ov = { o.x, o.y, o.z, o.w };                            \
              __builtin_nontemporal_store(ov, (vfloat4*)(drow + (J) * 4));    \
          } }

        PCEN4(v0, 0) PCEN4(v1, 1) PCEN4(v2, 2) PCEN4(v3, 3)
        PCEN4(v4, 4) PCEN4(v5, 5) PCEN4(v6, 6) PCEN4(v7, 7)
#undef PCEN4
#undef PCEN1
    }

    if (PASS == 0) {
        // wave reduce (u-domain)
        for (int off = 32; off >= 1; off >>= 1) {
            vmin = fminf(vmin, __shfl_xor(vmin, off, 64));
            vmax = fmaxf(vmax, __shfl_xor(vmax, off, 64));
        }
        __shared__ unsigned int smin, smax;
        if (tid == 0) { smin = 0xFFFFFFFFu; smax = 0u; }
        __syncthreads();
        if (lane == 0 && active) {
            atomicMin(&smin, flip_f(vmin));
            atomicMax(&smax, flip_f(vmax));
        }
        __syncthreads();
        if (tid == 0) {
            // convert u-extrema -> p-domain (p = u^r monotone; minmax of both
            // endpoints handles either sign of r). Same instruction sequence
            // as PASS 1 per-element path -> bitwise-identical at extremes.
            const float umin = unflip_f(smin);
            const float umax = unflip_f(smax);
            const float pl = fexp2(r * flog2(umin));
            const float ph = fexp2(r * flog2(umax));
            atomicMin(&ws[0], flip_f(fminf(pl, ph)));
            atomicMax(&ws[1], flip_f(fmaxf(pl, ph)));
        }
    }
}

extern "C" void kernel_launch(void* const* d_in, const int* in_sizes, int n_in,
                              void* d_out, int out_size, void* d_ws, size_t ws_size,
                              hipStream_t stream) {
    const float* E     = (const float*)d_in[0];
    const float* s     = (const float*)d_in[1];
    const float* alpha = (const float*)d_in[2];
    const float* delta = (const float*)d_in[3];
    const float* r     = (const float*)d_in[4];
    float* out         = (float*)d_out;
    unsigned int* ws   = (unsigned int*)d_ws;

    const int rows   = in_sizes[0] / T_LEN;   // 8192 for (32,256,4096)
    const int blocks = (rows + 1) / 2;        // 2 rows per 256-thread block (2 waves/row)

    hipLaunchKernelGGL(init_ws, dim3(1), dim3(1), 0, stream, ws);
    hipLaunchKernelGGL((pcen_pass<0>), dim3(blocks), dim3(256), 0, stream,
                       E, s, alpha, delta, r, out, ws, rows);
    hipLaunchKernelGGL((pcen_pass<1>), dim3(blocks), dim3(256), 0, stream,
                       E, s, alpha, delta, r, out, ws, rows);
}

// Round 4
// 304.338 us; speedup vs baseline: 1.9361x; 1.9361x over previous
//
#include <hip/hip_runtime.h>

static constexpr int T_LEN = 4096;          // time axis length
static constexpr int GROUPS = T_LEN / 256;  // 16 groups of 256 elems per wave-row
#define EPSV 1e-6f

typedef float vfloat4 __attribute__((ext_vector_type(4)));

// raw hw transcendentals: exp2/log2
__device__ __forceinline__ float fexp2(float x) { return __builtin_amdgcn_exp2f(x); }
__device__ __forceinline__ float flog2(float x) { return __builtin_amdgcn_logf(x); }

// order-preserving float<->uint transform (works for negatives too)
__device__ __forceinline__ unsigned int flip_f(float f) {
    unsigned int u = __float_as_uint(f);
    return u ^ ((u >> 31) ? 0xFFFFFFFFu : 0x80000000u);
}
__device__ __forceinline__ float unflip_f(unsigned int u) {
    u ^= ((u >> 31) ? 0x80000000u : 0xFFFFFFFFu);
    return __uint_as_float(u);
}

__global__ void init_ws(unsigned int* ws) {
    ws[0] = 0xFFFFFFFFu;  // min slot (transformed +max)
    ws[1] = 0x00000000u;  // max slot (transformed -max)
}

// PASS A: round-0-proven streaming scan (1 wave = 1 row, 16 groups, 1-deep
// prefetch, 6-shfl scan per group). Computes u = E*(eps+M)^-alpha + delta
// (2 transcendentals/elem; the pow-r is deferred to pcen_norm), stores u to
// out (REGULAR store -> L3-resident for pass B), tracks u-domain min/max
// (monotone pre-pow; validated rounds 1-3), converts to p-domain per block.
// NOTE (rounds 1-3): any design holding >=8 float4 of row data live across
// the scan went to memory traffic (~370MB extra WRITE, VALUBusy 5%). Keep
// the live float4 set to {cur, nxt, o} as in round 0.
__launch_bounds__(256, 4)
__global__ void pcen_scan(const float* __restrict__ E,
                          const float* __restrict__ sp,
                          const float* __restrict__ ap,
                          const float* __restrict__ dp,
                          const float* __restrict__ rp,
                          float* __restrict__ out,
                          unsigned int* __restrict__ ws,
                          int rows)
{
    const int tid  = threadIdx.x;
    const int lane = tid & 63;
    const int wv   = tid >> 6;
    const int row  = blockIdx.x * 4 + wv;

    float s = sp[0];
    s = fminf(fmaxf(s, 0.0f), 1.0f);
    const float a     = 1.0f - s;
    const float alpha = ap[0];
    const float delta = dp[0];
    const float r     = rp[0];
    const float na    = -alpha;

    // powers of a for the lane scan (ratio per lane-chunk is a^4)
    const float a2 = a * a, a4 = a2 * a2, a8 = a4 * a4, a16 = a8 * a8,
                a32 = a16 * a16, a64 = a32 * a32, a128 = a64 * a64,
                a256 = a128 * a128;
    float pwl;  // a^(4*lane)
    if (a > 0.0f) pwl = fexp2((float)(4 * lane) * flog2(a));
    else          pwl = (lane == 0) ? 1.0f : 0.0f;

    float vmin = __builtin_inff(), vmax = -__builtin_inff();

    if (row < rows) {
        const float4* __restrict__ src = (const float4*)(E + (size_t)row * T_LEN);
        float* __restrict__ drow = out + (size_t)row * T_LEN;

        // seed: since a+s==1, carry=E[0] makes uniform recurrence yield M[0]=E[0]
        float carry = E[(size_t)row * T_LEN];
        float4 cur = src[lane];

        for (int g = 0; g < GROUPS; ++g) {
            float4 nxt = make_float4(0.f, 0.f, 0.f, 0.f);
            if (g + 1 < GROUPS) nxt = src[(g + 1) * 64 + lane];  // prefetch

            // local weighted sum over this lane's 4 elements (Horner)
            float b = cur.x;
            b = __builtin_fmaf(a, b, cur.y);
            b = __builtin_fmaf(a, b, cur.z);
            b = __builtin_fmaf(a, b, cur.w);
            float B = s * b;

            // inclusive wave scan: B_i += a^(4k) * B_{i-k}
            float t;
            t = __shfl_up(B, 1, 64);  if (lane >= 1)  B = __builtin_fmaf(a4,   t, B);
            t = __shfl_up(B, 2, 64);  if (lane >= 2)  B = __builtin_fmaf(a8,   t, B);
            t = __shfl_up(B, 4, 64);  if (lane >= 4)  B = __builtin_fmaf(a16,  t, B);
            t = __shfl_up(B, 8, 64);  if (lane >= 8)  B = __builtin_fmaf(a32,  t, B);
            t = __shfl_up(B, 16, 64); if (lane >= 16) B = __builtin_fmaf(a64,  t, B);
            t = __shfl_up(B, 32, 64); if (lane >= 32) B = __builtin_fmaf(a128, t, B);

            float Bex = __shfl_up(B, 1, 64);
            if (lane == 0) Bex = 0.0f;
            const float B63 = __shfl(B, 63, 64);

            float m = __builtin_fmaf(pwl, carry, Bex);   // M just before this lane's chunk
            carry   = __builtin_fmaf(a256, carry, B63);  // M at end of group

            float4 o;
            float x, u;

            x = cur.x;
            m = __builtin_fmaf(a, m, s * x);
            u = __builtin_fmaf(x, fexp2(na * flog2(EPSV + m)), delta);
            vmin = fminf(vmin, u); vmax = fmaxf(vmax, u);
            o.x = u;

            x = cur.y;
            m = __builtin_fmaf(a, m, s * x);
            u = __builtin_fmaf(x, fexp2(na * flog2(EPSV + m)), delta);
            vmin = fminf(vmin, u); vmax = fmaxf(vmax, u);
            o.y = u;

            x = cur.z;
            m = __builtin_fmaf(a, m, s * x);
            u = __builtin_fmaf(x, fexp2(na * flog2(EPSV + m)), delta);
            vmin = fminf(vmin, u); vmax = fmaxf(vmax, u);
            o.z = u;

            x = cur.w;
            m = __builtin_fmaf(a, m, s * x);
            u = __builtin_fmaf(x, fexp2(na * flog2(EPSV + m)), delta);
            vmin = fminf(vmin, u); vmax = fmaxf(vmax, u);
            o.w = u;

            // regular (cached) store: u must stay L3-resident for pcen_norm
            vfloat4 ov = { o.x, o.y, o.z, o.w };
            *((vfloat4*)(drow + (size_t)(g * 64 + lane) * 4)) = ov;

            cur = nxt;
        }
    }

    // wave reduce (u-domain)
    for (int off = 32; off >= 1; off >>= 1) {
        vmin = fminf(vmin, __shfl_xor(vmin, off, 64));
        vmax = fmaxf(vmax, __shfl_xor(vmax, off, 64));
    }
    __shared__ unsigned int smin, smax;
    if (tid == 0) { smin = 0xFFFFFFFFu; smax = 0u; }
    __syncthreads();
    if (lane == 0 && row < rows) {
        atomicMin(&smin, flip_f(vmin));
        atomicMax(&smax, flip_f(vmax));
    }
    __syncthreads();
    if (tid == 0) {
        // convert u-extrema -> p-domain (p = u^r monotone; minmax of both
        // endpoints handles either sign of r). Same instruction sequence as
        // pcen_norm's per-element path -> bitwise-identical at the extremes.
        const float umin = unflip_f(smin);
        const float umax = unflip_f(smax);
        const float pl = fexp2(r * flog2(umin));
        const float ph = fexp2(r * flog2(umax));
        atomicMin(&ws[0], flip_f(fminf(pl, ph)));
        atomicMax(&ws[1], flip_f(fmaxf(pl, ph)));
    }
}

// PASS B: pure elementwise normalize, in place on out (which holds u).
// p = u^r via exp2(r*log2(u)); o = fma(p, scale, bias). No scan, no shfl.
// Reads are L3-hot (u just written). NT store: result never re-read.
__launch_bounds__(256, 8)
__global__ void pcen_norm(float* __restrict__ out,
                          const float* __restrict__ rp,
                          const unsigned int* __restrict__ ws,
                          int n4)
{
    const float r    = rp[0];
    const float pmin = unflip_f(ws[0]);
    const float pmax = unflip_f(ws[1]);
    const float inv  = 2.0f / (pmax - pmin);
    const float bias = __builtin_fmaf(-pmin, inv, -1.0f);

    const vfloat4* __restrict__ ip = (const vfloat4*)out;
    vfloat4* __restrict__ op = (vfloat4*)out;

    int idx = blockIdx.x * 256 + threadIdx.x;
    const int stride = gridDim.x * 256;
    for (; idx < n4; idx += stride) {
        vfloat4 u = ip[idx];
        vfloat4 o;
        o.x = __builtin_fmaf(fexp2(r * flog2(u.x)), inv, bias);
        o.y = __builtin_fmaf(fexp2(r * flog2(u.y)), inv, bias);
        o.z = __builtin_fmaf(fexp2(r * flog2(u.z)), inv, bias);
        o.w = __builtin_fmaf(fexp2(r * flog2(u.w)), inv, bias);
        __builtin_nontemporal_store(o, op + idx);
    }
}

extern "C" void kernel_launch(void* const* d_in, const int* in_sizes, int n_in,
                              void* d_out, int out_size, void* d_ws, size_t ws_size,
                              hipStream_t stream) {
    const float* E     = (const float*)d_in[0];
    const float* s     = (const float*)d_in[1];
    const float* alpha = (const float*)d_in[2];
    const float* delta = (const float*)d_in[3];
    const float* r     = (const float*)d_in[4];
    float* out         = (float*)d_out;
    unsigned int* ws   = (unsigned int*)d_ws;

    const int rows   = in_sizes[0] / T_LEN;   // 8192 for (32,256,4096)
    const int blocks = (rows + 3) / 4;        // 4 rows (waves) per 256-thread block

    const int n4      = (rows * T_LEN) / 4;   // float4 count for pass B
    const int blocks1 = 2048;                 // grid-stride elementwise

    hipLaunchKernelGGL(init_ws, dim3(1), dim3(1), 0, stream, ws);
    hipLaunchKernelGGL(pcen_scan, dim3(blocks), dim3(256), 0, stream,
                       E, s, alpha, delta, r, out, ws, rows);
    hipLaunchKernelGGL(pcen_norm, dim3(blocks1), dim3(256), 0, stream,
                       out, r, ws, n4);
}

// Round 5
// 287.812 us; speedup vs baseline: 2.0473x; 1.0574x over previous
//
#include <hip/hip_runtime.h>

static constexpr int T_LEN  = 4096;          // time axis length
static constexpr int GROUPS = T_LEN / 512;   // 8 groups of 512 elems per wave-row
#define EPSV 1e-6f

typedef float vfloat4 __attribute__((ext_vector_type(4)));

// raw hw transcendentals: exp2/log2
__device__ __forceinline__ float fexp2(float x) { return __builtin_amdgcn_exp2f(x); }
__device__ __forceinline__ float flog2(float x) { return __builtin_amdgcn_logf(x); }

// order-preserving float<->uint transform (works for negatives too)
__device__ __forceinline__ unsigned int flip_f(float f) {
    unsigned int u = __float_as_uint(f);
    return u ^ ((u >> 31) ? 0xFFFFFFFFu : 0x80000000u);
}
__device__ __forceinline__ float unflip_f(unsigned int u) {
    u ^= ((u >> 31) ? 0x80000000u : 0xFFFFFFFFu);
    return __uint_as_float(u);
}

__global__ void init_ws(unsigned int* ws) {
    ws[0] = 0xFFFFFFFFu;  // min slot (transformed +max)
    ws[1] = 0x00000000u;  // max slot (transformed -max)
}

// Streaming scan, 1 wave = 1 row. Round-5 change: 8 elems/lane per group
// (512/group, 8 groups) -> HALF the serial shfl ladders vs round 4 (the
// measured limiter: VALUBusy 14%, HBM 24%, i.e. chain-latency-bound).
// Computes u = E*(eps+M)^-alpha + delta (pow-r deferred to pcen_norm),
// stores u to out (REGULAR store -> L3-resident for pass B), tracks
// u-domain min/max, converts to p-domain once per block at the end.
// NOTE (rounds 1-3): designs holding a row chunk live ACROSS the scan +
// barrier blew up into scratch traffic. Keep the live float4 set small
// and strictly streaming: {cur0,cur1,nxt0,nxt1,o0,o1}.
__launch_bounds__(256, 4)
__global__ void pcen_scan(const float* __restrict__ E,
                          const float* __restrict__ sp,
                          const float* __restrict__ ap,
                          const float* __restrict__ dp,
                          const float* __restrict__ rp,
                          float* __restrict__ out,
                          unsigned int* __restrict__ ws,
                          int rows)
{
    const int tid  = threadIdx.x;
    const int lane = tid & 63;
    const int wv   = tid >> 6;
    const int row  = blockIdx.x * 4 + wv;

    float s = sp[0];
    s = fminf(fmaxf(s, 0.0f), 1.0f);
    const float a     = 1.0f - s;
    const float alpha = ap[0];
    const float delta = dp[0];
    const float r     = rp[0];
    const float na    = -alpha;

    // powers of a by repeated squaring (lane chunk = 8 elems -> ratio a^8)
    const float a2 = a * a, a4 = a2 * a2, a8 = a4 * a4, a16 = a8 * a8,
                a32 = a16 * a16, a64 = a32 * a32, a128 = a64 * a64,
                a256 = a128 * a128, a512 = a256 * a256;
    float pwl;  // a^(8*lane)
    if (a > 0.0f) pwl = fexp2((float)(8 * lane) * flog2(a));
    else          pwl = (lane == 0) ? 1.0f : 0.0f;

    float vmin = __builtin_inff(), vmax = -__builtin_inff();

    if (row < rows) {
        const float4* __restrict__ src = (const float4*)(E + (size_t)row * T_LEN);
        float* __restrict__ drow = out + (size_t)row * T_LEN;

        // seed: since a+s==1, carry=E[0] makes uniform recurrence yield M[0]=E[0]
        float carry = E[(size_t)row * T_LEN];
        float4 cur0 = src[lane * 2];
        float4 cur1 = src[lane * 2 + 1];

        for (int g = 0; g < GROUPS; ++g) {
            float4 nxt0 = make_float4(0.f, 0.f, 0.f, 0.f);
            float4 nxt1 = make_float4(0.f, 0.f, 0.f, 0.f);
            if (g + 1 < GROUPS) {                       // prefetch next group
                nxt0 = src[(g + 1) * 128 + lane * 2];
                nxt1 = src[(g + 1) * 128 + lane * 2 + 1];
            }

            // lane-local weighted sum over 8 elems: B = s * sum a^(7-i) x_i
            // two interleaved even/odd Horner chains (ratio a^2, depth 4)
            float c0 = cur0.x, c1 = cur0.y;
            c0 = __builtin_fmaf(a2, c0, cur0.z);  c1 = __builtin_fmaf(a2, c1, cur0.w);
            c0 = __builtin_fmaf(a2, c0, cur1.x);  c1 = __builtin_fmaf(a2, c1, cur1.y);
            c0 = __builtin_fmaf(a2, c0, cur1.z);  c1 = __builtin_fmaf(a2, c1, cur1.w);
            float B = s * __builtin_fmaf(a, c0, c1);

            // inclusive wave scan, lane ratio a^8: B_L += a^(8k) * B_{L-k}
            float t;
            t = __shfl_up(B, 1, 64);  if (lane >= 1)  B = __builtin_fmaf(a8,   t, B);
            t = __shfl_up(B, 2, 64);  if (lane >= 2)  B = __builtin_fmaf(a16,  t, B);
            t = __shfl_up(B, 4, 64);  if (lane >= 4)  B = __builtin_fmaf(a32,  t, B);
            t = __shfl_up(B, 8, 64);  if (lane >= 8)  B = __builtin_fmaf(a64,  t, B);
            t = __shfl_up(B, 16, 64); if (lane >= 16) B = __builtin_fmaf(a128, t, B);
            t = __shfl_up(B, 32, 64); if (lane >= 32) B = __builtin_fmaf(a256, t, B);

            float Bex = __shfl_up(B, 1, 64);
            if (lane == 0) Bex = 0.0f;
            const float B63 = __shfl(B, 63, 64);

            float m = __builtin_fmaf(pwl, carry, Bex);   // M just before lane's chunk
            carry   = __builtin_fmaf(a512, carry, B63);  // M at end of group

            float4 o0, o1;
#define PCEN_U(X, OREF)                                                          \
            { const float x = (X);                                               \
              m = __builtin_fmaf(a, m, s * x);                                   \
              const float u = __builtin_fmaf(x, fexp2(na * flog2(EPSV + m)), delta); \
              vmin = fminf(vmin, u); vmax = fmaxf(vmax, u);                      \
              OREF = u; }
            PCEN_U(cur0.x, o0.x) PCEN_U(cur0.y, o0.y)
            PCEN_U(cur0.z, o0.z) PCEN_U(cur0.w, o0.w)
            PCEN_U(cur1.x, o1.x) PCEN_U(cur1.y, o1.y)
            PCEN_U(cur1.z, o1.z) PCEN_U(cur1.w, o1.w)
#undef PCEN_U

            // regular (cached) stores: u must stay L3-resident for pcen_norm
            const size_t base = (size_t)g * 512 + (size_t)lane * 8;
            vfloat4 s0 = { o0.x, o0.y, o0.z, o0.w };
            vfloat4 s1 = { o1.x, o1.y, o1.z, o1.w };
            *((vfloat4*)(drow + base))     = s0;
            *((vfloat4*)(drow + base + 4)) = s1;

            cur0 = nxt0;
            cur1 = nxt1;
        }
    }

    // wave reduce (u-domain)
    for (int off = 32; off >= 1; off >>= 1) {
        vmin = fminf(vmin, __shfl_xor(vmin, off, 64));
        vmax = fmaxf(vmax, __shfl_xor(vmax, off, 64));
    }
    __shared__ unsigned int smin, smax;
    if (tid == 0) { smin = 0xFFFFFFFFu; smax = 0u; }
    __syncthreads();
    if (lane == 0 && row < rows) {
        atomicMin(&smin, flip_f(vmin));
        atomicMax(&smax, flip_f(vmax));
    }
    __syncthreads();
    if (tid == 0) {
        // convert u-extrema -> p-domain (p = u^r monotone; minmax of both
        // endpoints handles either sign of r). Same instruction sequence as
        // pcen_norm's per-element path -> bitwise-identical at the extremes.
        const float umin = unflip_f(smin);
        const float umax = unflip_f(smax);
        const float pl = fexp2(r * flog2(umin));
        const float ph = fexp2(r * flog2(umax));
        atomicMin(&ws[0], flip_f(fminf(pl, ph)));
        atomicMax(&ws[1], flip_f(fmaxf(pl, ph)));
    }
}

// PASS B: pure elementwise normalize, in place on out (which holds u).
// p = u^r via exp2(r*log2(u)); o = fma(p, scale, bias). 2x ILP per iter.
// Reads are L3-hot (u just written). NT store: result never re-read.
__launch_bounds__(256, 8)
__global__ void pcen_norm(float* __restrict__ out,
                          const float* __restrict__ rp,
                          const unsigned int* __restrict__ ws,
                          int n4)
{
    const float r    = rp[0];
    const float pmin = unflip_f(ws[0]);
    const float pmax = unflip_f(ws[1]);
    const float inv  = 2.0f / (pmax - pmin);
    const float bias = __builtin_fmaf(-pmin, inv, -1.0f);

    const vfloat4* __restrict__ ip = (const vfloat4*)out;
    vfloat4* __restrict__ op = (vfloat4*)out;

    int idx = (blockIdx.x * 256 + threadIdx.x) * 2;
    const int stride = gridDim.x * 256 * 2;
    for (; idx < n4; idx += stride) {
        vfloat4 u0 = ip[idx];
        const bool has1 = (idx + 1 < n4);
        vfloat4 u1 = has1 ? ip[idx + 1] : u0;

        vfloat4 o0, o1;
        o0.x = __builtin_fmaf(fexp2(r * flog2(u0.x)), inv, bias);
        o0.y = __builtin_fmaf(fexp2(r * flog2(u0.y)), inv, bias);
        o0.z = __builtin_fmaf(fexp2(r * flog2(u0.z)), inv, bias);
        o0.w = __builtin_fmaf(fexp2(r * flog2(u0.w)), inv, bias);
        o1.x = __builtin_fmaf(fexp2(r * flog2(u1.x)), inv, bias);
        o1.y = __builtin_fmaf(fexp2(r * flog2(u1.y)), inv, bias);
        o1.z = __builtin_fmaf(fexp2(r * flog2(u1.z)), inv, bias);
        o1.w = __builtin_fmaf(fexp2(r * flog2(u1.w)), inv, bias);

        __builtin_nontemporal_store(o0, op + idx);
        if (has1) __builtin_nontemporal_store(o1, op + idx + 1);
    }
}

extern "C" void kernel_launch(void* const* d_in, const int* in_sizes, int n_in,
                              void* d_out, int out_size, void* d_ws, size_t ws_size,
                              hipStream_t stream) {
    const float* E     = (const float*)d_in[0];
    const float* s     = (const float*)d_in[1];
    const float* alpha = (const float*)d_in[2];
    const float* delta = (const float*)d_in[3];
    const float* r     = (const float*)d_in[4];
    float* out         = (float*)d_out;
    unsigned int* ws   = (unsigned int*)d_ws;

    const int rows   = in_sizes[0] / T_LEN;   // 8192 for (32,256,4096)
    const int blocks = (rows + 3) / 4;        // 4 rows (waves) per 256-thread block

    const int n4      = (rows * T_LEN) / 4;   // float4 count for pass B
    const int blocks1 = 2048;                 // grid-stride elementwise

    hipLaunchKernelGGL(init_ws, dim3(1), dim3(1), 0, stream, ws);
    hipLaunchKernelGGL(pcen_scan, dim3(blocks), dim3(256), 0, stream,
                       E, s, alpha, delta, r, out, ws, rows);
    hipLaunchKernelGGL(pcen_norm, dim3(blocks1), dim3(256), 0, stream,
                       out, r, ws, n4);
}